// Round 8
// baseline (60.715 us; speedup 1.0000x reference)
//
#include <hip/hip_runtime.h>

#define L 32768           // 32*32*32
#define NC 96
#define LDS_FLOATS (32 * 1057)          // A(i,j,k) = i*1057 + j*33 + k
#define LDS_BYTES  (LDS_FLOATS * 4)     // 135,296 B (<160 KB/CU)

typedef float f4 __attribute__((ext_vector_type(4)));

// Output: out[b][s][c][l], s in 0..11.  flip = s+2
// q0->s0: l=i*1024+j*32+k   q1->s1: l=i*1024+k*32+j
// q2->s4: l=j*1024+k*32+i   q3->s5: l=j*1024+i*32+k
// q4->s8: l=k*1024+i*32+j   q5->s9: l=k*1024+j*32+i
// input addr = i*1024 + j*32 + k
//
// One block per (b,c) slice, read once. EVERY store stream ascending:
// flip scans gather reversed data (u = 8191-t, reverse4) instead of writing
// descending. One stream per phase, barrier-separated -> 192 concurrent
// ascending streams device-wide.

__global__ __launch_bounds__(1024) void cross_scan3d(const float* __restrict__ in,
                                                     float* __restrict__ out) {
    extern __shared__ float lds[];

    const int bc  = blockIdx.x;        // b*96 + c
    const int b   = bc / NC;
    const int c   = bc % NC;
    const int tid = threadIdx.x;

    const f4* src4 = (const f4*)(in + (size_t)bc * L);
    #define OPTR(s) ((f4*)(out + ((size_t)((b)*12 + (s)) * NC + (c)) * L))
    #define NT(p, v) __builtin_nontemporal_store((v), (p))
    #define A(i, j, k) ((i) * 1057 + (j) * 33 + (k))

    // gathers: u = source f4 index in scan-q ordering
    #define G0(v, u) { int i=(u)>>8, j=((u)>>3)&31, kb=((u)&7)*4;               \
        v.x=lds[A(i,j,kb+0)]; v.y=lds[A(i,j,kb+1)];                             \
        v.z=lds[A(i,j,kb+2)]; v.w=lds[A(i,j,kb+3)]; }
    #define G1(v, u) { int i=(u)>>8, k=((u)>>3)&31, jb=((u)&7)*4;               \
        v.x=lds[A(i,jb+0,k)]; v.y=lds[A(i,jb+1,k)];                             \
        v.z=lds[A(i,jb+2,k)]; v.w=lds[A(i,jb+3,k)]; }
    #define G2(v, u) { int j=(u)>>8, k=((u)>>3)&31, ib=((u)&7)*4;               \
        v.x=lds[A(ib+0,j,k)]; v.y=lds[A(ib+1,j,k)];                             \
        v.z=lds[A(ib+2,j,k)]; v.w=lds[A(ib+3,j,k)]; }
    #define G3(v, u) { int j=(u)>>8, i=((u)>>3)&31, kb=((u)&7)*4;               \
        v.x=lds[A(i,j,kb+0)]; v.y=lds[A(i,j,kb+1)];                             \
        v.z=lds[A(i,j,kb+2)]; v.w=lds[A(i,j,kb+3)]; }
    #define G4(v, u) { int k=(u)>>8, i=((u)>>3)&31, jb=((u)&7)*4;               \
        v.x=lds[A(i,jb+0,k)]; v.y=lds[A(i,jb+1,k)];                             \
        v.z=lds[A(i,jb+2,k)]; v.w=lds[A(i,jb+3,k)]; }
    #define G5(v, u) { int k=(u)>>8, j=((u)>>3)&31, ib=((u)&7)*4;               \
        v.x=lds[A(ib+0,j,k)]; v.y=lds[A(ib+1,j,k)];                             \
        v.z=lds[A(ib+2,j,k)]; v.w=lds[A(ib+3,j,k)]; }

    // base phase: ascending gather + ascending store
    #define PHASE_BASE(Gm, optr)                                                \
        _Pragma("unroll")                                                       \
        for (int it = 0; it < 8; ++it) {                                        \
            int t = it * 1024 + tid;                                            \
            f4 v; Gm(v, t);                                                     \
            NT((optr) + t, v);                                                  \
        }                                                                       \
        __syncthreads();

    // flip phase: ascending store of reversed gather
    #define PHASE_FLIP(Gm, optr)                                                \
        _Pragma("unroll")                                                       \
        for (int it = 0; it < 8; ++it) {                                        \
            int t = it * 1024 + tid;                                            \
            int u = 8191 - t;                                                   \
            f4 v; Gm(v, u);                                                     \
            f4 r = { v.w, v.z, v.y, v.x };                                      \
            NT((optr) + t, r);                                                  \
        }                                                                       \
        __syncthreads();

    // ---- load whole slice once; q0 emitted straight from registers ----
    {
        f4* o0 = OPTR(0);
        #pragma unroll
        for (int it = 0; it < 8; ++it) {
            int t = it * 1024 + tid;               // t = i*256 + j*8 + k4
            f4 v = __builtin_nontemporal_load(src4 + t);
            int i = t >> 8, j = (t >> 3) & 31, kb = (t & 7) * 4;
            float* d = &lds[A(i, j, kb)];
            d[0] = v.x; d[1] = v.y; d[2] = v.z; d[3] = v.w;
            NT(o0 + t, v);
        }
        __syncthreads();
    }

    PHASE_FLIP(G0, OPTR(2))     // q0f
    PHASE_BASE(G1, OPTR(1))     // q1
    PHASE_FLIP(G1, OPTR(3))     // q1f
    PHASE_BASE(G3, OPTR(5))     // q3
    PHASE_FLIP(G3, OPTR(7))     // q3f
    PHASE_BASE(G2, OPTR(4))     // q2
    PHASE_FLIP(G2, OPTR(6))     // q2f
    PHASE_BASE(G4, OPTR(8))     // q4
    PHASE_FLIP(G4, OPTR(10))    // q4f
    PHASE_BASE(G5, OPTR(9))     // q5
    PHASE_FLIP(G5, OPTR(11))    // q5f

    #undef OPTR
    #undef NT
    #undef A
}

extern "C" void kernel_launch(void* const* d_in, const int* in_sizes, int n_in,
                              void* d_out, int out_size, void* d_ws, size_t ws_size,
                              hipStream_t stream) {
    const float* in = (const float*)d_in[0];
    float* out = (float*)d_out;
    const int bc_count = in_sizes[0] / L;   // B*C = 192

    // allow >64KB dynamic LDS (host-side attribute, graph-capture safe)
    (void)hipFuncSetAttribute((const void*)cross_scan3d,
                              hipFuncAttributeMaxDynamicSharedMemorySize, LDS_BYTES);

    cross_scan3d<<<dim3(bc_count), 1024, LDS_BYTES, stream>>>(in, out);
}

// Round 9
// 59.011 us; speedup vs baseline: 1.0289x; 1.0289x over previous
//
#include <hip/hip_runtime.h>

#define L 32768           // 32*32*32
#define NC 96
#define LDS_FLOATS (32 * 1057)          // A(i,j,k) = i*1057 + j*33 + k
#define LDS_BYTES  (LDS_FLOATS * 4)     // 135,296 B (<160 KB/CU)

typedef float f4 __attribute__((ext_vector_type(4)));

// Output: out[b][s][c][l], s in 0..11.  flip = s+2
// q0->s0: l=i*1024+j*32+k   q1->s1: l=i*1024+k*32+j
// q2->s4: l=j*1024+k*32+i   q3->s5: l=j*1024+i*32+k
// q4->s8: l=k*1024+i*32+j   q5->s9: l=k*1024+j*32+i
// input addr = i*1024 + j*32 + k
//
// One block per (b,c) slice, input read once. All streams ascending,
// phase-serialized. R9: PLAIN stores (L2 writeback aggregation) instead of
// NT, + XCD-contiguous bc swizzle (each XCD owns 24 consecutive slices).

__global__ __launch_bounds__(1024) void cross_scan3d(const float* __restrict__ in,
                                                     float* __restrict__ out) {
    extern __shared__ float lds[];

    // XCD swizzle: dispatch round-robins blockIdx%8 -> XCD. Give XCD x the
    // contiguous bc range [24x, 24x+24). 192 = 8*24 exactly (bijective).
    const int g   = blockIdx.x;
    const int bc  = (g & 7) * 24 + (g >> 3);
    const int b   = bc / NC;
    const int c   = bc % NC;
    const int tid = threadIdx.x;

    const f4* src4 = (const f4*)(in + (size_t)bc * L);
    #define OPTR(s) ((f4*)(out + ((size_t)((b)*12 + (s)) * NC + (c)) * L))
    #define A(i, j, k) ((i) * 1057 + (j) * 33 + (k))

    // gathers: u = source f4 index in scan-q ordering
    #define G0(v, u) { int i=(u)>>8, j=((u)>>3)&31, kb=((u)&7)*4;               \
        v.x=lds[A(i,j,kb+0)]; v.y=lds[A(i,j,kb+1)];                             \
        v.z=lds[A(i,j,kb+2)]; v.w=lds[A(i,j,kb+3)]; }
    #define G1(v, u) { int i=(u)>>8, k=((u)>>3)&31, jb=((u)&7)*4;               \
        v.x=lds[A(i,jb+0,k)]; v.y=lds[A(i,jb+1,k)];                             \
        v.z=lds[A(i,jb+2,k)]; v.w=lds[A(i,jb+3,k)]; }
    #define G2(v, u) { int j=(u)>>8, k=((u)>>3)&31, ib=((u)&7)*4;               \
        v.x=lds[A(ib+0,j,k)]; v.y=lds[A(ib+1,j,k)];                             \
        v.z=lds[A(ib+2,j,k)]; v.w=lds[A(ib+3,j,k)]; }
    #define G3(v, u) { int j=(u)>>8, i=((u)>>3)&31, kb=((u)&7)*4;               \
        v.x=lds[A(i,j,kb+0)]; v.y=lds[A(i,j,kb+1)];                             \
        v.z=lds[A(i,j,kb+2)]; v.w=lds[A(i,j,kb+3)]; }
    #define G4(v, u) { int k=(u)>>8, i=((u)>>3)&31, jb=((u)&7)*4;               \
        v.x=lds[A(i,jb+0,k)]; v.y=lds[A(i,jb+1,k)];                             \
        v.z=lds[A(i,jb+2,k)]; v.w=lds[A(i,jb+3,k)]; }
    #define G5(v, u) { int k=(u)>>8, j=((u)>>3)&31, ib=((u)&7)*4;               \
        v.x=lds[A(ib+0,j,k)]; v.y=lds[A(ib+1,j,k)];                             \
        v.z=lds[A(ib+2,j,k)]; v.w=lds[A(ib+3,j,k)]; }

    // base phase: ascending gather + ascending plain store
    #define PHASE_BASE(Gm, optr)                                                \
        _Pragma("unroll")                                                       \
        for (int it = 0; it < 8; ++it) {                                        \
            int t = it * 1024 + tid;                                            \
            f4 v; Gm(v, t);                                                     \
            (optr)[t] = v;                                                      \
        }                                                                       \
        __syncthreads();

    // flip phase: ascending store of reversed gather
    #define PHASE_FLIP(Gm, optr)                                                \
        _Pragma("unroll")                                                       \
        for (int it = 0; it < 8; ++it) {                                        \
            int t = it * 1024 + tid;                                            \
            int u = 8191 - t;                                                   \
            f4 v; Gm(v, u);                                                     \
            f4 r = { v.w, v.z, v.y, v.x };                                      \
            (optr)[t] = r;                                                      \
        }                                                                       \
        __syncthreads();

    // ---- load whole slice once; q0 emitted straight from registers ----
    {
        f4* o0 = OPTR(0);
        #pragma unroll
        for (int it = 0; it < 8; ++it) {
            int t = it * 1024 + tid;               // t = i*256 + j*8 + k4
            f4 v = src4[t];
            int i = t >> 8, j = (t >> 3) & 31, kb = (t & 7) * 4;
            float* d = &lds[A(i, j, kb)];
            d[0] = v.x; d[1] = v.y; d[2] = v.z; d[3] = v.w;
            o0[t] = v;
        }
        __syncthreads();
    }

    PHASE_FLIP(G0, OPTR(2))     // q0f
    PHASE_BASE(G1, OPTR(1))     // q1
    PHASE_FLIP(G1, OPTR(3))     // q1f
    PHASE_BASE(G3, OPTR(5))     // q3
    PHASE_FLIP(G3, OPTR(7))     // q3f
    PHASE_BASE(G2, OPTR(4))     // q2
    PHASE_FLIP(G2, OPTR(6))     // q2f
    PHASE_BASE(G4, OPTR(8))     // q4
    PHASE_FLIP(G4, OPTR(10))    // q4f
    PHASE_BASE(G5, OPTR(9))     // q5
    PHASE_FLIP(G5, OPTR(11))    // q5f

    #undef OPTR
    #undef A
}

extern "C" void kernel_launch(void* const* d_in, const int* in_sizes, int n_in,
                              void* d_out, int out_size, void* d_ws, size_t ws_size,
                              hipStream_t stream) {
    const float* in = (const float*)d_in[0];
    float* out = (float*)d_out;
    const int bc_count = in_sizes[0] / L;   // B*C = 192

    // allow >64KB dynamic LDS (host-side attribute, graph-capture safe)
    (void)hipFuncSetAttribute((const void*)cross_scan3d,
                              hipFuncAttributeMaxDynamicSharedMemorySize, LDS_BYTES);

    cross_scan3d<<<dim3(bc_count), 1024, LDS_BYTES, stream>>>(in, out);
}